// Round 1
// baseline (5432.718 us; speedup 1.0000x reference)
//
#include <hip/hip_runtime.h>
#include <math.h>

#define NB 16
#define CC 576
#define HH 12
#define WW 20
#define PP 240     // HH*WW
#define MM 3840    // NB*PP
#define KK 5184    // CC*9
#define NHEAD 8

__device__ __forceinline__ float sigmoidf_(float x) {
    return 1.0f / (1.0f + expf(-x));
}

// ---------------- Kernel A: channel means + linear head + single_out ------
__global__ __launch_bounds__(256) void k_single(const float* __restrict__ f,
                                                const float* __restrict__ linW,
                                                const float* __restrict__ linb,
                                                float* __restrict__ out) {
    int n = blockIdx.x;
    __shared__ float f1[CC];
    __shared__ float lin[10];
    int t = threadIdx.x;
    int lane = t & 63, wave = t >> 6;
    const float* fn = f + (size_t)n * CC * PP;
    for (int c = wave; c < CC; c += 4) {
        const float* row = fn + c * PP;
        float s = 0.f;
        for (int p = lane; p < PP; p += 64) s += row[p];
        #pragma unroll
        for (int off = 32; off; off >>= 1) s += __shfl_xor(s, off, 64);
        if (lane == 0) f1[c] = s * (1.0f / PP);
    }
    __syncthreads();
    if (t < 10) {
        const float* wrow = linW + t * CC;
        float s = linb[t];
        for (int c = 0; c < CC; ++c) s = fmaf(f1[c], wrow[c], s);
        lin[t] = s;
    }
    __syncthreads();
    if (t == 0) {
        const float eps = 1e-5f;
        float conf = sigmoidf_(lin[0]);
        conf = fminf(fmaxf(conf, eps), 1.f - eps);
        int best = 0; float bv = lin[1];
        #pragma unroll
        for (int j = 1; j < 5; ++j) { if (lin[1 + j] > bv) { bv = lin[1 + j]; best = j; } }
        float dist = 3.f * sigmoidf_(lin[6]);
        float offs = tanhf(lin[7]);
        float sev  = fminf(fmaxf(sigmoidf_(lin[8]), eps), 1.f - eps);
        float surf = fminf(fmaxf(sigmoidf_(lin[9]), eps), 1.f - eps);
        float* o = out + n * 6;
        o[0] = conf; o[1] = (float)best; o[2] = dist;
        o[3] = offs; o[4] = sev; o[5] = surf;
    }
}

// ---------------- Kernel B: implicit-GEMM conv3x3 + BN + SiLU -------------
// h[m][c] = silu(bn(sum_k A[m,k]*B[k,c])), A = im2col(f), B = w1 head slice.
// Tile 64x64, BK=16, 4x4 microtile per thread (256 threads).
#define BKC 16
#define LDT 72   // padded LDS row stride (16B-aligned float4 rows)

__global__ __launch_bounds__(256) void k_conv_gemm(
        const float* __restrict__ f,
        const float* __restrict__ w1,     // head base: [c][k], k = ci*9+dy*3+dx
        const float* __restrict__ bng, const float* __restrict__ bnb,
        const float* __restrict__ bnm, const float* __restrict__ bnv,
        float* __restrict__ hout) {
    __shared__ __align__(16) float As[BKC][LDT];  // [k][m]
    __shared__ __align__(16) float Bs[BKC][LDT];  // [k][c]
    int t = threadIdx.x;
    int m0 = blockIdx.x * 64;
    int c0 = blockIdx.y * 64;

    // A-load mapping: 64 lanes = rows, wave id picks k-quad
    int a_row = t & 63;
    int a_ks  = (t >> 6) * 4;
    int m  = m0 + a_row;
    int n_ = m / PP; int p = m - n_ * PP;
    int y  = p / WW; int x = p - y * WW;
    const float* fbase = f + (size_t)n_ * (CC * PP);

    // B-load mapping: c = t>>2, k-quad = (t&3)*4 (float4 along k)
    int b_c = t >> 2;
    int b_k = (t & 3) * 4;
    const float* wrow = w1 + (size_t)(c0 + b_c) * KK + b_k;

    float acc[4][4] = {};
    int ty = t >> 4, tx = t & 15;

    for (int kb = 0; kb < KK; kb += BKC) {
        #pragma unroll
        for (int j = 0; j < 4; ++j) {
            int k  = kb + a_ks + j;
            int ci = k / 9; int r = k - ci * 9;
            int dy = r / 3; int dx = r - dy * 3;
            int yy = y + dy - 1, xx = x + dx - 1;
            float v = 0.f;
            if ((unsigned)yy < (unsigned)HH && (unsigned)xx < (unsigned)WW)
                v = fbase[(ci * HH + yy) * WW + xx];
            As[a_ks + j][a_row] = v;
        }
        float4 bv = *(const float4*)(wrow + kb);
        Bs[b_k + 0][b_c] = bv.x;
        Bs[b_k + 1][b_c] = bv.y;
        Bs[b_k + 2][b_c] = bv.z;
        Bs[b_k + 3][b_c] = bv.w;
        __syncthreads();
        #pragma unroll
        for (int kk = 0; kk < BKC; ++kk) {
            float4 a4 = *(const float4*)&As[kk][ty * 4];
            float4 b4 = *(const float4*)&Bs[kk][tx * 4];
            float av[4] = {a4.x, a4.y, a4.z, a4.w};
            float bw[4] = {b4.x, b4.y, b4.z, b4.w};
            #pragma unroll
            for (int i = 0; i < 4; ++i)
                #pragma unroll
                for (int jj = 0; jj < 4; ++jj)
                    acc[i][jj] = fmaf(av[i], bw[jj], acc[i][jj]);
        }
        __syncthreads();
    }
    // epilogue: batchnorm affine + SiLU, store h_act[m][c]
    #pragma unroll
    for (int jj = 0; jj < 4; ++jj) {
        int c = c0 + tx * 4 + jj;
        float g = bng[c], bb = bnb[c], bm = bnm[c], bvv = bnv[c];
        float scale = g / sqrtf(bvv + 1e-5f);
        float shift = bb - bm * scale;
        #pragma unroll
        for (int i = 0; i < 4; ++i) {
            int mrow = m0 + ty * 4 + i;
            float h = fmaf(acc[i][jj], scale, shift);
            float s = h * sigmoidf_(h);
            hout[(size_t)mrow * CC + c] = s;
        }
    }
}

// ---------------- Kernel C: project h (576) -> head's out channels --------
__global__ __launch_bounds__(256) void k_proj(
        const float* __restrict__ h,    // [MM][CC]
        const float* __restrict__ w2,   // [14][CC]
        const float* __restrict__ b2,   // [14]
        float* __restrict__ maps,       // [NB][14][PP]
        int o0, int o1) {
    int wave = threadIdx.x >> 6, lane = threadIdx.x & 63;
    int m = blockIdx.x * 4 + wave;
    const float* hrow = h + (size_t)m * CC;
    float hv[9];
    #pragma unroll
    for (int j = 0; j < 9; ++j) hv[j] = hrow[lane + 64 * j];
    int n = m / PP, p = m - n * PP;
    for (int o = o0; o < o1; ++o) {
        const float* wr = w2 + o * CC;
        float s = 0.f;
        #pragma unroll
        for (int j = 0; j < 9; ++j) s = fmaf(hv[j], wr[lane + 64 * j], s);
        #pragma unroll
        for (int off = 32; off; off >>= 1) s += __shfl_xor(s, off, 64);
        if (lane == 0) maps[(n * 14 + o) * PP + p] = s + b2[o];
    }
}

// ---------------- Kernel D: decode + top-k + distance sort ----------------
__global__ __launch_bounds__(256) void k_decode(
        const float* __restrict__ maps,  // [NB][14][PP]
        const int* __restrict__ fw_p, const int* __restrict__ fh_p,
        float* __restrict__ out) {
    int n = blockIdx.x;
    int t = threadIdx.x;
    __shared__ float ms[14][PP];
    __shared__ float sconf[PP];
    __shared__ float cscore[100];
    __shared__ int   cidx[100];
    __shared__ float dets[100][10];
    __shared__ float dvals[100];

    const float* mp = maps + (size_t)n * 14 * PP;
    for (int idx = t; idx < 14 * PP; idx += 256) ms[idx / PP][idx % PP] = mp[idx];
    __syncthreads();
    if (t < PP) sconf[t] = sigmoidf_(ms[5][t]);
    __syncthreads();

    // top-20 per class, one wave per class (stable: ties -> lower index)
    int wv = t >> 6, lane = t & 63;
    for (int cls = wv; cls < 5; cls += 4) {
        float v[4]; int pi[4];
        #pragma unroll
        for (int j = 0; j < 4; ++j) {
            int p = lane + 64 * j;
            pi[j] = p;
            v[j] = (p < PP) ? sconf[p] * sigmoidf_(ms[cls][p]) : -1e30f;
        }
        for (int r = 0; r < 20; ++r) {
            float bv = v[0]; int bi = pi[0];
            #pragma unroll
            for (int j = 1; j < 4; ++j)
                if (v[j] > bv || (v[j] == bv && pi[j] < bi)) { bv = v[j]; bi = pi[j]; }
            float rv = bv; int ri = bi;
            #pragma unroll
            for (int off = 32; off; off >>= 1) {
                float ov = __shfl_xor(rv, off, 64);
                int   oi = __shfl_xor(ri, off, 64);
                if (ov > rv || (ov == rv && oi < ri)) { rv = ov; ri = oi; }
            }
            if (lane == 0) { cscore[cls * 20 + r] = rv; cidx[cls * 20 + r] = ri; }
            #pragma unroll
            for (int j = 0; j < 4; ++j) if (pi[j] == ri) v[j] = -1e30f;
        }
    }
    __syncthreads();

    if (t < 100) {
        int cls = t / 20;
        int p = cidx[t];
        int yi = p / WW, xi = p - yi * WW;
        float gx = sigmoidf_(ms[6][p]),  gy = sigmoidf_(ms[7][p]);
        float gw = sigmoidf_(ms[8][p]),  gh = sigmoidf_(ms[9][p]);
        float gd = 3.f * sigmoidf_(ms[10][p]);
        float go = tanhf(ms[11][p]);
        float gs = sigmoidf_(ms[12][p]);
        float gf = sigmoidf_(ms[13][p]);
        float fw = (float)fw_p[0], fh = (float)fh_p[0];
        float sx = fw / (float)WW, sy = fh / (float)HH;
        float cx = fminf(fmaxf((float)xi + gx, 0.f), (float)WW - 1.f) * sx;
        float cy = fminf(fmaxf((float)yi + gy, 0.f), (float)HH - 1.f) * sy;
        float bw = fminf(fmaxf(gw, 0.f), 1.f) * fw;
        float bh = fminf(fmaxf(gh, 0.f), 1.f) * fh;
        float x1 = fminf(fmaxf(cx - bw * 0.5f, 0.f), fw - 1.f);
        float y1 = fminf(fmaxf(cy - bh * 0.5f, 0.f), fh - 1.f);
        float x2 = fminf(fmaxf(cx + bw * 0.5f, 0.f), fw - 1.f);
        float y2 = fminf(fmaxf(cy + bh * 0.5f, 0.f), fh - 1.f);
        dets[t][0] = cscore[t]; dets[t][1] = (float)cls;
        dets[t][2] = gd; dets[t][3] = go; dets[t][4] = gs; dets[t][5] = gf;
        dets[t][6] = x1; dets[t][7] = y1; dets[t][8] = x2; dets[t][9] = y2;
        dvals[t] = gd;
    }
    __syncthreads();
    if (t < 100) {
        float d = dvals[t];
        int rank = 0;
        for (int l = 0; l < 100; ++l) {
            float dl = dvals[l];
            rank += (dl < d) || (dl == d && l < t);
        }
        if (rank < 20) {
            float* o = out + 96 + ((size_t)n * 20 + rank) * 10;
            #pragma unroll
            for (int q = 0; q < 10; ++q) o[q] = dets[t][q];
        }
    }
}

extern "C" void kernel_launch(void* const* d_in, const int* in_sizes, int n_in,
                              void* d_out, int out_size, void* d_ws, size_t ws_size,
                              hipStream_t stream) {
    const float* f    = (const float*)d_in[0];
    const float* w1   = (const float*)d_in[1];
    const float* bng  = (const float*)d_in[2];
    const float* bnb  = (const float*)d_in[3];
    const float* bnm  = (const float*)d_in[4];
    const float* bnv  = (const float*)d_in[5];
    const float* w2   = (const float*)d_in[6];
    const float* b2   = (const float*)d_in[7];
    const float* linW = (const float*)d_in[8];
    const float* linb = (const float*)d_in[9];
    const int*   fw   = (const int*)d_in[10];
    const int*   fh   = (const int*)d_in[11];
    float* out = (float*)d_out;

    float* ws_h    = (float*)d_ws;                   // MM*CC floats (8.85 MB)
    float* ws_maps = ws_h + (size_t)MM * CC;         // NB*14*PP floats

    k_single<<<NB, 256, 0, stream>>>(f, linW, linb, out);

    static const int OFFS_h[NHEAD + 1] = {0, 5, 6, 8, 10, 11, 12, 13, 14};
    for (int i = 0; i < NHEAD; ++i) {
        k_conv_gemm<<<dim3(MM / 64, CC / 64), 256, 0, stream>>>(
            f, w1 + (size_t)i * CC * KK,
            bng + i * CC, bnb + i * CC, bnm + i * CC, bnv + i * CC, ws_h);
        k_proj<<<MM / 4, 256, 0, stream>>>(ws_h, w2, b2, ws_maps,
                                           OFFS_h[i], OFFS_h[i + 1]);
    }
    k_decode<<<NB, 256, 0, stream>>>(ws_maps, fw, fh, out);
}

// Round 2
// 3192.601 us; speedup vs baseline: 1.7017x; 1.7017x over previous
//
#include <hip/hip_runtime.h>
#include <math.h>

#define NB 16
#define CC 576
#define HH 12
#define WW 20
#define PP 240     // HH*WW
#define MM 3840    // NB*PP
#define KK 5184    // CC*9
#define NHEAD 8

__device__ __forceinline__ float sigmoidf_(float x) {
    return 1.0f / (1.0f + expf(-x));
}

// ---------------- Kernel A: channel means + linear head + single_out ------
__global__ __launch_bounds__(256) void k_single(const float* __restrict__ f,
                                                const float* __restrict__ linW,
                                                const float* __restrict__ linb,
                                                float* __restrict__ out) {
    int n = blockIdx.x;
    __shared__ float f1[CC];
    __shared__ float lin[10];
    int t = threadIdx.x;
    int lane = t & 63, wave = t >> 6;
    const float* fn = f + (size_t)n * CC * PP;
    for (int c = wave; c < CC; c += 4) {
        const float* row = fn + c * PP;
        float s = 0.f;
        for (int p = lane; p < PP; p += 64) s += row[p];
        #pragma unroll
        for (int off = 32; off; off >>= 1) s += __shfl_xor(s, off, 64);
        if (lane == 0) f1[c] = s * (1.0f / PP);
    }
    __syncthreads();
    if (t < 10) {
        const float* wrow = linW + t * CC;
        float s = linb[t];
        for (int c = 0; c < CC; ++c) s = fmaf(f1[c], wrow[c], s);
        lin[t] = s;
    }
    __syncthreads();
    if (t == 0) {
        const float eps = 1e-5f;
        float conf = sigmoidf_(lin[0]);
        conf = fminf(fmaxf(conf, eps), 1.f - eps);
        int best = 0; float bv = lin[1];
        #pragma unroll
        for (int j = 1; j < 5; ++j) { if (lin[1 + j] > bv) { bv = lin[1 + j]; best = j; } }
        float dist = 3.f * sigmoidf_(lin[6]);
        float offs = tanhf(lin[7]);
        float sev  = fminf(fmaxf(sigmoidf_(lin[8]), eps), 1.f - eps);
        float surf = fminf(fmaxf(sigmoidf_(lin[9]), eps), 1.f - eps);
        float* o = out + n * 6;
        o[0] = conf; o[1] = (float)best; o[2] = dist;
        o[3] = offs; o[4] = sev; o[5] = surf;
    }
}

// ---------------- transpose f[n][c][p] -> ft[n][p][c] ---------------------
__global__ __launch_bounds__(256) void k_tr_f(const float* __restrict__ f,
                                              float* __restrict__ ft) {
    __shared__ float tile[32][33];
    int c0 = blockIdx.x * 32, p0 = blockIdx.y * 32, n = blockIdx.z;
    int tp = threadIdx.x & 31, tc8 = threadIdx.x >> 5;
    for (int cc = tc8; cc < 32; cc += 8) {
        int p = p0 + tp;
        tile[cc][tp] = (p < PP) ? f[((size_t)n * CC + c0 + cc) * PP + p] : 0.f;
    }
    __syncthreads();
    int tcw = threadIdx.x & 31, tpw = threadIdx.x >> 5;
    for (int pp = tpw; pp < 32; pp += 8) {
        int p = p0 + pp;
        if (p < PP) ft[((size_t)n * PP + p) * CC + c0 + tcw] = tile[tcw][pp];
    }
}

// ---------------- transpose w1[h][co][ci][tap] -> wt[h][tap][ci][co] ------
__global__ __launch_bounds__(256) void k_tr_w(const float* __restrict__ w1,
                                              float* __restrict__ wt) {
    size_t x = (size_t)blockIdx.x * 256 + threadIdx.x;
    if (x >= (size_t)NHEAD * CC * CC) return;
    int co = (int)(x % CC); int rest = (int)(x / CC);
    int ci = rest % CC; int h = rest / CC;
    const float* src = w1 + (((size_t)h * CC + co) * CC + ci) * 9;
    #pragma unroll
    for (int tap = 0; tap < 9; ++tap)
        wt[(((size_t)(h * 9 + tap) * CC + ci) * CC) + co] = src[tap];
}

// ---------------- init maps with bias -------------------------------------
__global__ __launch_bounds__(256) void k_maps_init(float* __restrict__ maps,
                                                   const float* __restrict__ b2) {
    int i = blockIdx.x * 256 + threadIdx.x;
    if (i < NB * 14 * PP) {
        int o = (i / PP) % 14;
        maps[i] = b2[o];
    }
}

// ---------------- fused conv3x3 GEMM + BN + SiLU + projection -------------
// One dispatch for all 8 heads. grid (60, 9, 8). Tile 64m x 64co, BK=16 ci,
// tap loop outer. A from ft (coalesced), B from wt (coalesced).
__global__ __launch_bounds__(256, 6) void k_conv_fused(
        const float* __restrict__ ft,     // [MM][CC]
        const float* __restrict__ wt,     // [h][tap][ci][co]
        const float* __restrict__ w2,     // [14][CC]
        const float* __restrict__ bng, const float* __restrict__ bnb,
        const float* __restrict__ bnm, const float* __restrict__ bnv,
        float* __restrict__ maps) {
    __shared__ __align__(16) float As[16][72];   // [ci][m]
    __shared__ __align__(16) float Bs[16][72];   // [ci][co]
    __shared__ int rowoff[9][64];                // [tap][row] base into ft, -1 = OOB

    int t = threadIdx.x;
    int h = blockIdx.z;
    int m0 = blockIdx.x * 64;
    int c0 = blockIdx.y * 64;

    for (int idx = t; idx < 9 * 64; idx += 256) {
        int tap = idx >> 6, row = idx & 63;
        int m = m0 + row;
        int n = m / PP, p = m - n * PP;
        int y = p / WW, x = p - y * WW;
        int yy = y + (tap / 3) - 1;
        int xx = x + (tap % 3) - 1;
        rowoff[tap][row] =
            ((unsigned)yy < (unsigned)HH && (unsigned)xx < (unsigned)WW)
                ? (n * PP + yy * WW + xx) * CC : -1;
    }
    __syncthreads();

    float acc[4][4] = {};
    int ci_l = t & 15;          // A-load channel lane
    int rsub = t >> 4;          // A-load row subgroup (0..15)
    int b_co = t & 63;          // B-load co lane
    int b_kg = (t >> 6) * 4;    // B-load k quad
    int ty = t >> 4, tx = t & 15;
    const float* wth = wt + (size_t)h * 9 * CC * CC;

    for (int tap = 0; tap < 9; ++tap) {
        const float* wtt = wth + (size_t)tap * CC * CC + c0 + b_co;
        for (int cib = 0; cib < CC; cib += 16) {
            #pragma unroll
            for (int ps = 0; ps < 4; ++ps) {
                int row = rsub + ps * 16;
                int off = rowoff[tap][row];
                float v = 0.f;
                if (off >= 0) v = ft[off + cib + ci_l];
                As[ci_l][row] = v;
            }
            const float* wrow = wtt + (size_t)(cib + b_kg) * CC;
            #pragma unroll
            for (int j = 0; j < 4; ++j)
                Bs[b_kg + j][b_co] = wrow[(size_t)j * CC];
            __syncthreads();
            #pragma unroll
            for (int kk = 0; kk < 16; ++kk) {
                float4 a4 = *(const float4*)&As[kk][ty * 4];
                float4 b4 = *(const float4*)&Bs[kk][tx * 4];
                float av[4] = {a4.x, a4.y, a4.z, a4.w};
                float bw[4] = {b4.x, b4.y, b4.z, b4.w};
                #pragma unroll
                for (int i = 0; i < 4; ++i)
                    #pragma unroll
                    for (int jj = 0; jj < 4; ++jj)
                        acc[i][jj] = fmaf(av[i], bw[jj], acc[i][jj]);
            }
            __syncthreads();
        }
    }

    // epilogue: BN + SiLU
    float hv[4][4];
    #pragma unroll
    for (int jj = 0; jj < 4; ++jj) {
        int c = c0 + tx * 4 + jj;
        float g = bng[h * CC + c], bb = bnb[h * CC + c];
        float bm = bnm[h * CC + c], bvv = bnv[h * CC + c];
        float scale = g / sqrtf(bvv + 1e-5f);
        float shift = bb - bm * scale;
        #pragma unroll
        for (int i = 0; i < 4; ++i) {
            float x = fmaf(acc[i][jj], scale, shift);
            hv[i][jj] = x * sigmoidf_(x);
        }
    }

    // fused projection: partial over this block's 64 channels -> atomicAdd
    static const int OFF[NHEAD + 1] = {0, 5, 6, 8, 10, 11, 12, 13, 14};
    int o0 = OFF[h], o1 = OFF[h + 1];
    for (int o = o0; o < o1; ++o) {
        float w2v[4];
        #pragma unroll
        for (int jj = 0; jj < 4; ++jj) w2v[jj] = w2[o * CC + c0 + tx * 4 + jj];
        float po[4];
        #pragma unroll
        for (int i = 0; i < 4; ++i) {
            float s = 0.f;
            #pragma unroll
            for (int jj = 0; jj < 4; ++jj) s = fmaf(hv[i][jj], w2v[jj], s);
            po[i] = s;
        }
        #pragma unroll
        for (int off = 1; off < 16; off <<= 1)
            #pragma unroll
            for (int i = 0; i < 4; ++i) po[i] += __shfl_xor(po[i], off, 64);
        if (tx == 0) {
            #pragma unroll
            for (int i = 0; i < 4; ++i) {
                int m = m0 + ty * 4 + i;
                int n = m / PP, p = m - n * PP;
                atomicAdd(&maps[(n * 14 + o) * PP + p], po[i]);
            }
        }
    }
}

// ---------------- FALLBACK (ws too small): round-1 conv + proj ------------
#define BKC 16
#define LDT 72

__global__ __launch_bounds__(256) void k_conv_gemm(
        const float* __restrict__ f,
        const float* __restrict__ w1,
        const float* __restrict__ bng, const float* __restrict__ bnb,
        const float* __restrict__ bnm, const float* __restrict__ bnv,
        float* __restrict__ hout) {
    __shared__ __align__(16) float As[BKC][LDT];
    __shared__ __align__(16) float Bs[BKC][LDT];
    int t = threadIdx.x;
    int m0 = blockIdx.x * 64;
    int c0 = blockIdx.y * 64;
    int a_row = t & 63;
    int a_ks  = (t >> 6) * 4;
    int m  = m0 + a_row;
    int n_ = m / PP; int p = m - n_ * PP;
    int y  = p / WW; int x = p - y * WW;
    const float* fbase = f + (size_t)n_ * (CC * PP);
    int b_c = t >> 2;
    int b_k = (t & 3) * 4;
    const float* wrow = w1 + (size_t)(c0 + b_c) * KK + b_k;
    float acc[4][4] = {};
    int ty = t >> 4, tx = t & 15;
    for (int kb = 0; kb < KK; kb += BKC) {
        #pragma unroll
        for (int j = 0; j < 4; ++j) {
            int k  = kb + a_ks + j;
            int ci = k / 9; int r = k - ci * 9;
            int dy = r / 3; int dx = r - dy * 3;
            int yy = y + dy - 1, xx = x + dx - 1;
            float v = 0.f;
            if ((unsigned)yy < (unsigned)HH && (unsigned)xx < (unsigned)WW)
                v = fbase[(ci * HH + yy) * WW + xx];
            As[a_ks + j][a_row] = v;
        }
        float4 bv = *(const float4*)(wrow + kb);
        Bs[b_k + 0][b_c] = bv.x;
        Bs[b_k + 1][b_c] = bv.y;
        Bs[b_k + 2][b_c] = bv.z;
        Bs[b_k + 3][b_c] = bv.w;
        __syncthreads();
        #pragma unroll
        for (int kk = 0; kk < BKC; ++kk) {
            float4 a4 = *(const float4*)&As[kk][ty * 4];
            float4 b4 = *(const float4*)&Bs[kk][tx * 4];
            float av[4] = {a4.x, a4.y, a4.z, a4.w};
            float bw[4] = {b4.x, b4.y, b4.z, b4.w};
            #pragma unroll
            for (int i = 0; i < 4; ++i)
                #pragma unroll
                for (int jj = 0; jj < 4; ++jj)
                    acc[i][jj] = fmaf(av[i], bw[jj], acc[i][jj]);
        }
        __syncthreads();
    }
    #pragma unroll
    for (int jj = 0; jj < 4; ++jj) {
        int c = c0 + tx * 4 + jj;
        float g = bng[c], bb = bnb[c], bm = bnm[c], bvv = bnv[c];
        float scale = g / sqrtf(bvv + 1e-5f);
        float shift = bb - bm * scale;
        #pragma unroll
        for (int i = 0; i < 4; ++i) {
            int mrow = m0 + ty * 4 + i;
            float hx = fmaf(acc[i][jj], scale, shift);
            hout[(size_t)mrow * CC + c] = hx * sigmoidf_(hx);
        }
    }
}

__global__ __launch_bounds__(256) void k_proj(
        const float* __restrict__ h,
        const float* __restrict__ w2,
        const float* __restrict__ b2,
        float* __restrict__ maps,
        int o0, int o1) {
    int wave = threadIdx.x >> 6, lane = threadIdx.x & 63;
    int m = blockIdx.x * 4 + wave;
    const float* hrow = h + (size_t)m * CC;
    float hvv[9];
    #pragma unroll
    for (int j = 0; j < 9; ++j) hvv[j] = hrow[lane + 64 * j];
    int n = m / PP, p = m - n * PP;
    for (int o = o0; o < o1; ++o) {
        const float* wr = w2 + o * CC;
        float s = 0.f;
        #pragma unroll
        for (int j = 0; j < 9; ++j) s = fmaf(hvv[j], wr[lane + 64 * j], s);
        #pragma unroll
        for (int off = 32; off; off >>= 1) s += __shfl_xor(s, off, 64);
        if (lane == 0) maps[(n * 14 + o) * PP + p] = s + b2[o];
    }
}

// ---------------- Kernel D: decode + top-k + distance sort ----------------
__global__ __launch_bounds__(256) void k_decode(
        const float* __restrict__ maps,
        const int* __restrict__ fw_p, const int* __restrict__ fh_p,
        float* __restrict__ out) {
    int n = blockIdx.x;
    int t = threadIdx.x;
    __shared__ float ms[14][PP];
    __shared__ float sconf[PP];
    __shared__ float cscore[100];
    __shared__ int   cidx[100];
    __shared__ float dets[100][10];
    __shared__ float dvals[100];

    const float* mp = maps + (size_t)n * 14 * PP;
    for (int idx = t; idx < 14 * PP; idx += 256) ms[idx / PP][idx % PP] = mp[idx];
    __syncthreads();
    if (t < PP) sconf[t] = sigmoidf_(ms[5][t]);
    __syncthreads();

    int wv = t >> 6, lane = t & 63;
    for (int cls = wv; cls < 5; cls += 4) {
        float v[4]; int pi[4];
        #pragma unroll
        for (int j = 0; j < 4; ++j) {
            int p = lane + 64 * j;
            pi[j] = p;
            v[j] = (p < PP) ? sconf[p] * sigmoidf_(ms[cls][p]) : -1e30f;
        }
        for (int r = 0; r < 20; ++r) {
            float bv = v[0]; int bi = pi[0];
            #pragma unroll
            for (int j = 1; j < 4; ++j)
                if (v[j] > bv || (v[j] == bv && pi[j] < bi)) { bv = v[j]; bi = pi[j]; }
            float rv = bv; int ri = bi;
            #pragma unroll
            for (int off = 32; off; off >>= 1) {
                float ov = __shfl_xor(rv, off, 64);
                int   oi = __shfl_xor(ri, off, 64);
                if (ov > rv || (ov == rv && oi < ri)) { rv = ov; ri = oi; }
            }
            if (lane == 0) { cscore[cls * 20 + r] = rv; cidx[cls * 20 + r] = ri; }
            #pragma unroll
            for (int j = 0; j < 4; ++j) if (pi[j] == ri) v[j] = -1e30f;
        }
    }
    __syncthreads();

    if (t < 100) {
        int cls = t / 20;
        int p = cidx[t];
        int yi = p / WW, xi = p - yi * WW;
        float gx = sigmoidf_(ms[6][p]),  gy = sigmoidf_(ms[7][p]);
        float gw = sigmoidf_(ms[8][p]),  gh = sigmoidf_(ms[9][p]);
        float gd = 3.f * sigmoidf_(ms[10][p]);
        float go = tanhf(ms[11][p]);
        float gs = sigmoidf_(ms[12][p]);
        float gf = sigmoidf_(ms[13][p]);
        float fw = (float)fw_p[0], fh = (float)fh_p[0];
        float sx = fw / (float)WW, sy = fh / (float)HH;
        float cx = fminf(fmaxf((float)xi + gx, 0.f), (float)WW - 1.f) * sx;
        float cy = fminf(fmaxf((float)yi + gy, 0.f), (float)HH - 1.f) * sy;
        float bw = fminf(fmaxf(gw, 0.f), 1.f) * fw;
        float bh = fminf(fmaxf(gh, 0.f), 1.f) * fh;
        float x1 = fminf(fmaxf(cx - bw * 0.5f, 0.f), fw - 1.f);
        float y1 = fminf(fmaxf(cy - bh * 0.5f, 0.f), fh - 1.f);
        float x2 = fminf(fmaxf(cx + bw * 0.5f, 0.f), fw - 1.f);
        float y2 = fminf(fmaxf(cy + bh * 0.5f, 0.f), fh - 1.f);
        dets[t][0] = cscore[t]; dets[t][1] = (float)cls;
        dets[t][2] = gd; dets[t][3] = go; dets[t][4] = gs; dets[t][5] = gf;
        dets[t][6] = x1; dets[t][7] = y1; dets[t][8] = x2; dets[t][9] = y2;
        dvals[t] = gd;
    }
    __syncthreads();
    if (t < 100) {
        float d = dvals[t];
        int rank = 0;
        for (int l = 0; l < 100; ++l) {
            float dl = dvals[l];
            rank += (dl < d) || (dl == d && l < t);
        }
        if (rank < 20) {
            float* o = out + 96 + ((size_t)n * 20 + rank) * 10;
            #pragma unroll
            for (int q = 0; q < 10; ++q) o[q] = dets[t][q];
        }
    }
}

extern "C" void kernel_launch(void* const* d_in, const int* in_sizes, int n_in,
                              void* d_out, int out_size, void* d_ws, size_t ws_size,
                              hipStream_t stream) {
    const float* f    = (const float*)d_in[0];
    const float* w1   = (const float*)d_in[1];
    const float* bng  = (const float*)d_in[2];
    const float* bnb  = (const float*)d_in[3];
    const float* bnm  = (const float*)d_in[4];
    const float* bnv  = (const float*)d_in[5];
    const float* w2   = (const float*)d_in[6];
    const float* b2   = (const float*)d_in[7];
    const float* linW = (const float*)d_in[8];
    const float* linb = (const float*)d_in[9];
    const int*   fw   = (const int*)d_in[10];
    const int*   fh   = (const int*)d_in[11];
    float* out = (float*)d_out;

    k_single<<<NB, 256, 0, stream>>>(f, linW, linb, out);

    const size_t wt_elems   = (size_t)NHEAD * 9 * CC * CC;     // 23,887,872
    const size_t ft_elems   = (size_t)MM * CC;                 //  2,211,840
    const size_t maps_elems = (size_t)NB * 14 * PP;            //     53,760
    const size_t need = (wt_elems + ft_elems + maps_elems) * sizeof(float);

    if (ws_size >= need) {
        float* ws_wt   = (float*)d_ws;
        float* ws_ft   = ws_wt + wt_elems;
        float* ws_maps = ws_ft + ft_elems;

        k_tr_w<<<(int)((wt_elems / 9 + 255) / 256), 256, 0, stream>>>(w1, ws_wt);
        k_tr_f<<<dim3(CC / 32, (PP + 31) / 32, NB), 256, 0, stream>>>(f, ws_ft);
        k_maps_init<<<(int)((maps_elems + 255) / 256), 256, 0, stream>>>(ws_maps, b2);
        k_conv_fused<<<dim3(MM / 64, CC / 64, NHEAD), 256, 0, stream>>>(
            ws_ft, ws_wt, w2, bng, bnb, bnm, bnv, ws_maps);
        k_decode<<<NB, 256, 0, stream>>>(ws_maps, fw, fh, out);
    } else {
        float* ws_h    = (float*)d_ws;
        float* ws_maps = ws_h + (size_t)MM * CC;
        static const int OFFS_h[NHEAD + 1] = {0, 5, 6, 8, 10, 11, 12, 13, 14};
        for (int i = 0; i < NHEAD; ++i) {
            k_conv_gemm<<<dim3(MM / 64, CC / 64), 256, 0, stream>>>(
                f, w1 + (size_t)i * CC * KK,
                bng + i * CC, bnb + i * CC, bnm + i * CC, bnv + i * CC, ws_h);
            k_proj<<<MM / 4, 256, 0, stream>>>(ws_h, w2, b2, ws_maps,
                                               OFFS_h[i], OFFS_h[i + 1]);
        }
        k_decode<<<NB, 256, 0, stream>>>(ws_maps, fw, fh, out);
    }
}

// Round 3
// 1161.992 us; speedup vs baseline: 4.6753x; 2.7475x over previous
//
#include <hip/hip_runtime.h>
#include <math.h>

#define NB 16
#define CC 576
#define HH 12
#define WW 20
#define PP 240
#define MM 3840
#define NHEAD 8
#define HALO 22

typedef __attribute__((ext_vector_type(8))) short short8;
typedef __attribute__((ext_vector_type(4))) float floatx4;
typedef unsigned short ushort_t;

__device__ __forceinline__ float sigmoidf_(float x) {
    return 1.0f / (1.0f + expf(-x));
}
__device__ __forceinline__ unsigned short f2bf(float x) {
    union { float f; unsigned u; } v; v.f = x;
    unsigned r = v.u + 0x7fff + ((v.u >> 16) & 1);
    return (unsigned short)(r >> 16);
}
__device__ __forceinline__ float bf2f(unsigned short b) {
    union { float f; unsigned u; } v; v.u = ((unsigned)b) << 16;
    return v.f;
}

// ---------------- Kernel A: channel means + linear head + single_out ------
__global__ __launch_bounds__(256) void k_single(const float* __restrict__ f,
                                                const float* __restrict__ linW,
                                                const float* __restrict__ linb,
                                                float* __restrict__ out) {
    int n = blockIdx.x;
    __shared__ float f1[CC];
    __shared__ float lin[10];
    int t = threadIdx.x;
    int lane = t & 63, wave = t >> 6;
    const float* fn = f + (size_t)n * CC * PP;
    for (int c = wave; c < CC; c += 4) {
        const float* row = fn + c * PP;
        float s = 0.f;
        for (int p = lane; p < PP; p += 64) s += row[p];
        #pragma unroll
        for (int off = 32; off; off >>= 1) s += __shfl_xor(s, off, 64);
        if (lane == 0) f1[c] = s * (1.0f / PP);
    }
    __syncthreads();
    if (t < 10) {
        const float* wrow = linW + t * CC;
        float s = linb[t];
        for (int c = 0; c < CC; ++c) s = fmaf(f1[c], wrow[c], s);
        lin[t] = s;
    }
    __syncthreads();
    if (t == 0) {
        const float eps = 1e-5f;
        float conf = sigmoidf_(lin[0]);
        conf = fminf(fmaxf(conf, eps), 1.f - eps);
        int best = 0; float bv = lin[1];
        #pragma unroll
        for (int j = 1; j < 5; ++j) { if (lin[1 + j] > bv) { bv = lin[1 + j]; best = j; } }
        float dist = 3.f * sigmoidf_(lin[6]);
        float offs = tanhf(lin[7]);
        float sev  = fminf(fmaxf(sigmoidf_(lin[8]), eps), 1.f - eps);
        float surf = fminf(fmaxf(sigmoidf_(lin[9]), eps), 1.f - eps);
        float* o = out + n * 6;
        o[0] = conf; o[1] = (float)best; o[2] = dist;
        o[3] = offs; o[4] = sev; o[5] = surf;
    }
}

// ---------------- prep: f[n][c][p] -> ft_hi/ft_lo [m][c] bf16 -------------
__global__ __launch_bounds__(256) void k_prep_f(const float* __restrict__ f,
                                                ushort_t* __restrict__ fhi,
                                                ushort_t* __restrict__ flo) {
    __shared__ float tile[32][33];
    int c0 = blockIdx.x * 32, p0 = blockIdx.y * 32, n = blockIdx.z;
    int tp = threadIdx.x & 31, tc8 = threadIdx.x >> 5;
    for (int cc = tc8; cc < 32; cc += 8) {
        int p = p0 + tp;
        tile[cc][tp] = (p < PP) ? f[((size_t)n * CC + c0 + cc) * PP + p] : 0.f;
    }
    __syncthreads();
    int tcw = threadIdx.x & 31, tpw = threadIdx.x >> 5;
    for (int pp = tpw; pp < 32; pp += 8) {
        int p = p0 + pp;
        if (p < PP) {
            float v = tile[tcw][pp];
            unsigned short hi = f2bf(v);
            size_t o = ((size_t)n * PP + p) * CC + c0 + tcw;
            fhi[o] = hi;
            flo[o] = f2bf(v - bf2f(hi));
        }
    }
}

// ------ prep: w1[h][co][ci][tap] -> wt_hi/wt_lo [h][tap][co][ci] bf16 -----
__global__ __launch_bounds__(256) void k_prep_w(const float* __restrict__ w1,
                                                ushort_t* __restrict__ whi,
                                                ushort_t* __restrict__ wlo) {
    int co = blockIdx.x % CC;
    int h  = blockIdx.x / CC;
    const float* src = w1 + ((size_t)(h * CC + co)) * CC * 9;   // [ci][tap]
    for (int tap = 0; tap < 9; ++tap) {
        size_t ob = ((size_t)(h * 9 + tap) * CC + co) * CC;
        for (int ci = threadIdx.x; ci < CC; ci += 256) {
            float v = src[(size_t)ci * 9 + tap];
            unsigned short hi = f2bf(v);
            whi[ob + ci] = hi;
            wlo[ob + ci] = f2bf(v - bf2f(hi));
        }
    }
}

// ---------------- init maps with bias -------------------------------------
__global__ __launch_bounds__(256) void k_maps_init(float* __restrict__ maps,
                                                   const float* __restrict__ b2) {
    int i = blockIdx.x * 256 + threadIdx.x;
    if (i < NB * 14 * PP) {
        int o = (i / PP) % 14;
        maps[i] = b2[o];
    }
}

// ---------------- fused MFMA conv (bf16x3) + BN + SiLU + projection -------
// grid (15, 9, 8): m-tile 256, co-tile 64, head. 4 waves, wave-tile 64x64.
// A staged per ci-chunk (BK=32) with +/-22-row halo, shared across 9 taps
// via rowmap LUT. 3 MFMA passes (hi*hi, hi*lo, lo*hi) per fragment set.
__global__ __launch_bounds__(256) void k_conv_mfma(
        const ushort_t* __restrict__ fhi, const ushort_t* __restrict__ flo,
        const ushort_t* __restrict__ whi, const ushort_t* __restrict__ wlo,
        const float* __restrict__ w2,
        const float* __restrict__ bng, const float* __restrict__ bnb,
        const float* __restrict__ bnm, const float* __restrict__ bnv,
        float* __restrict__ maps) {
    // fragment-order LDS: chunk16(row,g) = (row>>4)*64 + g*16 + (row&15)
    __shared__ __align__(16) ushort_t Ah[1216 * 8];   // 304 rows x 32 k
    __shared__ __align__(16) ushort_t Al[1216 * 8];
    __shared__ __align__(16) ushort_t Bh[256 * 8];    // 64 co x 32 k
    __shared__ __align__(16) ushort_t Bl[256 * 8];
    __shared__ ushort_t rowmap[9 * 256];

    int t = threadIdx.x;
    int m0 = blockIdx.x * 256;
    int c0 = blockIdx.y * 64;
    int h  = blockIdx.z;

    // zero rows 300..303 (row-block 18, r&15 = 12..15) — never overwritten
    if (t < 32) {
        int arr = t >> 4, g = (t >> 2) & 3, rr = 12 + (t & 3);
        int idx = 18 * 64 + g * 16 + rr;
        short8 z = {0, 0, 0, 0, 0, 0, 0, 0};
        *(short8*)((arr ? Al : Ah) + idx * 8) = z;
    }
    // rowmap[tap][ml]: LDS A-row holding the tap-shifted source (300+x = zero)
    for (int idx = t; idx < 9 * 256; idx += 256) {
        int tap = idx >> 8, ml = idx & 255;
        int m = m0 + ml;
        int p = m % PP;
        int y = p / WW, x = p - y * WW;
        int dy = tap / 3 - 1, dx = tap % 3 - 1;
        int yy = y + dy, xx = x + dx;
        int row;
        if ((unsigned)yy < (unsigned)HH && (unsigned)xx < (unsigned)WW)
            row = ml + dy * WW + dx + HALO;
        else
            row = 300 + (ml & 3);
        rowmap[idx] = (ushort_t)row;
    }
    __syncthreads();

    floatx4 acc[4][4];
    #pragma unroll
    for (int i = 0; i < 4; ++i)
        #pragma unroll
        for (int j = 0; j < 4; ++j) acc[i][j] = (floatx4){0.f, 0.f, 0.f, 0.f};

    int w = t >> 6, lane = t & 63;
    int quad = lane >> 4, l15 = lane & 15;
    int srow_lo = t & 15, sg = (t >> 4) & 3, srb = t >> 6;

    for (int cib = 0; cib < 18; ++cib) {
        __syncthreads();
        int koff = cib * 32 + sg * 8;
        // stage A hi/lo: 5 iters, lane-linear LDS chunk index = 256*it + t
        #pragma unroll
        for (int it = 0; it < 5; ++it) {
            int row = (srb + 4 * it) * 16 + srow_lo;
            if (row < 300) {
                int mg = m0 - HALO + row;
                int cidx = 256 * it + t;
                short8 vh = {0, 0, 0, 0, 0, 0, 0, 0};
                short8 vl = {0, 0, 0, 0, 0, 0, 0, 0};
                if ((unsigned)mg < (unsigned)MM) {
                    vh = *(const short8*)(fhi + (size_t)mg * CC + koff);
                    vl = *(const short8*)(flo + (size_t)mg * CC + koff);
                }
                *(short8*)(Ah + cidx * 8) = vh;
                *(short8*)(Al + cidx * 8) = vl;
            }
        }
        for (int tap = 0; tap < 9; ++tap) {
            if (tap) __syncthreads();
            {   // stage B hi/lo: chunk index == t (lane-linear)
                int co = srb * 16 + srow_lo;
                size_t src = ((size_t)(h * 9 + tap) * CC + c0 + co) * CC + koff;
                *(short8*)(Bh + t * 8) = *(const short8*)(whi + src);
                *(short8*)(Bl + t * 8) = *(const short8*)(wlo + src);
            }
            __syncthreads();

            short8 bh[4], bl[4], ah[4], al[4];
            #pragma unroll
            for (int j = 0; j < 4; ++j) {
                bh[j] = *(const short8*)(Bh + (j * 64 + lane) * 8);
                bl[j] = *(const short8*)(Bl + (j * 64 + lane) * 8);
            }
            #pragma unroll
            for (int i = 0; i < 4; ++i) {
                int r = rowmap[tap * 256 + w * 64 + i * 16 + l15];
                int a16 = ((r >> 4) * 64 + quad * 16 + (r & 15)) * 8;
                ah[i] = *(const short8*)(Ah + a16);
                al[i] = *(const short8*)(Al + a16);
            }
            #pragma unroll
            for (int i = 0; i < 4; ++i)
                #pragma unroll
                for (int j = 0; j < 4; ++j) {
                    acc[i][j] = __builtin_amdgcn_mfma_f32_16x16x32_bf16(
                        ah[i], bh[j], acc[i][j], 0, 0, 0);
                    acc[i][j] = __builtin_amdgcn_mfma_f32_16x16x32_bf16(
                        ah[i], bl[j], acc[i][j], 0, 0, 0);
                    acc[i][j] = __builtin_amdgcn_mfma_f32_16x16x32_bf16(
                        al[i], bh[j], acc[i][j], 0, 0, 0);
                }
        }
    }

    // ---- epilogue: BN + SiLU, then fused projection ----
    float scale[4], shift[4];
    #pragma unroll
    for (int j = 0; j < 4; ++j) {
        int c = h * CC + c0 + j * 16 + l15;
        float g_ = bng[c], bb = bnb[c], bm = bnm[c], bv = bnv[c];
        scale[j] = g_ / sqrtf(bv + 1e-5f);
        shift[j] = bb - bm * scale[j];
    }
    #pragma unroll
    for (int i = 0; i < 4; ++i)
        #pragma unroll
        for (int j = 0; j < 4; ++j)
            #pragma unroll
            for (int r = 0; r < 4; ++r) {
                float hx = fmaf(acc[i][j][r], scale[j], shift[j]);
                acc[i][j][r] = hx * sigmoidf_(hx);
            }

    static const int OFFo[NHEAD + 1] = {0, 5, 6, 8, 10, 11, 12, 13, 14};
    int o0 = OFFo[h], o1 = OFFo[h + 1];
    for (int o = o0; o < o1; ++o) {
        float w2v[4];
        #pragma unroll
        for (int j = 0; j < 4; ++j) w2v[j] = w2[o * CC + c0 + j * 16 + l15];
        float pv[4][4];
        #pragma unroll
        for (int i = 0; i < 4; ++i)
            #pragma unroll
            for (int r = 0; r < 4; ++r) {
                float s = 0.f;
                #pragma unroll
                for (int j = 0; j < 4; ++j) s = fmaf(acc[i][j][r], w2v[j], s);
                pv[i][r] = s;
            }
        #pragma unroll
        for (int off = 1; off < 16; off <<= 1)
            #pragma unroll
            for (int i = 0; i < 4; ++i)
                #pragma unroll
                for (int r = 0; r < 4; ++r)
                    pv[i][r] += __shfl_xor(pv[i][r], off, 64);
        if (l15 == 0) {
            #pragma unroll
            for (int i = 0; i < 4; ++i)
                #pragma unroll
                for (int r = 0; r < 4; ++r) {
                    int m = m0 + w * 64 + i * 16 + quad * 4 + r;
                    int n = m / PP, p = m - n * PP;
                    atomicAdd(&maps[(n * 14 + o) * PP + p], pv[i][r]);
                }
        }
    }
}

// ---------------- Kernel D: decode + top-k + distance sort ----------------
__global__ __launch_bounds__(256) void k_decode(
        const float* __restrict__ maps,
        const int* __restrict__ fw_p, const int* __restrict__ fh_p,
        float* __restrict__ out) {
    int n = blockIdx.x;
    int t = threadIdx.x;
    __shared__ float ms[14][PP];
    __shared__ float sconf[PP];
    __shared__ float cscore[100];
    __shared__ int   cidx[100];
    __shared__ float dets[100][10];
    __shared__ float dvals[100];

    const float* mp = maps + (size_t)n * 14 * PP;
    for (int idx = t; idx < 14 * PP; idx += 256) ms[idx / PP][idx % PP] = mp[idx];
    __syncthreads();
    if (t < PP) sconf[t] = sigmoidf_(ms[5][t]);
    __syncthreads();

    int wv = t >> 6, lane = t & 63;
    for (int cls = wv; cls < 5; cls += 4) {
        float v[4]; int pi[4];
        #pragma unroll
        for (int j = 0; j < 4; ++j) {
            int p = lane + 64 * j;
            pi[j] = p;
            v[j] = (p < PP) ? sconf[p] * sigmoidf_(ms[cls][p]) : -1e30f;
        }
        for (int r = 0; r < 20; ++r) {
            float bv = v[0]; int bi = pi[0];
            #pragma unroll
            for (int j = 1; j < 4; ++j)
                if (v[j] > bv || (v[j] == bv && pi[j] < bi)) { bv = v[j]; bi = pi[j]; }
            float rv = bv; int ri = bi;
            #pragma unroll
            for (int off = 32; off; off >>= 1) {
                float ov = __shfl_xor(rv, off, 64);
                int   oi = __shfl_xor(ri, off, 64);
                if (ov > rv || (ov == rv && oi < ri)) { rv = ov; ri = oi; }
            }
            if (lane == 0) { cscore[cls * 20 + r] = rv; cidx[cls * 20 + r] = ri; }
            #pragma unroll
            for (int j = 0; j < 4; ++j) if (pi[j] == ri) v[j] = -1e30f;
        }
    }
    __syncthreads();

    if (t < 100) {
        int cls = t / 20;
        int p = cidx[t];
        int yi = p / WW, xi = p - yi * WW;
        float gx = sigmoidf_(ms[6][p]),  gy = sigmoidf_(ms[7][p]);
        float gw = sigmoidf_(ms[8][p]),  gh = sigmoidf_(ms[9][p]);
        float gd = 3.f * sigmoidf_(ms[10][p]);
        float go = tanhf(ms[11][p]);
        float gs = sigmoidf_(ms[12][p]);
        float gf = sigmoidf_(ms[13][p]);
        float fw = (float)fw_p[0], fh = (float)fh_p[0];
        float sx = fw / (float)WW, sy = fh / (float)HH;
        float cx = fminf(fmaxf((float)xi + gx, 0.f), (float)WW - 1.f) * sx;
        float cy = fminf(fmaxf((float)yi + gy, 0.f), (float)HH - 1.f) * sy;
        float bw = fminf(fmaxf(gw, 0.f), 1.f) * fw;
        float bh = fminf(fmaxf(gh, 0.f), 1.f) * fh;
        float x1 = fminf(fmaxf(cx - bw * 0.5f, 0.f), fw - 1.f);
        float y1 = fminf(fmaxf(cy - bh * 0.5f, 0.f), fh - 1.f);
        float x2 = fminf(fmaxf(cx + bw * 0.5f, 0.f), fw - 1.f);
        float y2 = fminf(fmaxf(cy + bh * 0.5f, 0.f), fh - 1.f);
        dets[t][0] = cscore[t]; dets[t][1] = (float)cls;
        dets[t][2] = gd; dets[t][3] = go; dets[t][4] = gs; dets[t][5] = gf;
        dets[t][6] = x1; dets[t][7] = y1; dets[t][8] = x2; dets[t][9] = y2;
        dvals[t] = gd;
    }
    __syncthreads();
    if (t < 100) {
        float d = dvals[t];
        int rank = 0;
        for (int l = 0; l < 100; ++l) {
            float dl = dvals[l];
            rank += (dl < d) || (dl == d && l < t);
        }
        if (rank < 20) {
            float* o = out + 96 + ((size_t)n * 20 + rank) * 10;
            #pragma unroll
            for (int q = 0; q < 10; ++q) o[q] = dets[t][q];
        }
    }
}

extern "C" void kernel_launch(void* const* d_in, const int* in_sizes, int n_in,
                              void* d_out, int out_size, void* d_ws, size_t ws_size,
                              hipStream_t stream) {
    const float* f    = (const float*)d_in[0];
    const float* w1   = (const float*)d_in[1];
    const float* bng  = (const float*)d_in[2];
    const float* bnb  = (const float*)d_in[3];
    const float* bnm  = (const float*)d_in[4];
    const float* bnv  = (const float*)d_in[5];
    const float* w2   = (const float*)d_in[6];
    const float* b2   = (const float*)d_in[7];
    const float* linW = (const float*)d_in[8];
    const float* linb = (const float*)d_in[9];
    const int*   fw   = (const int*)d_in[10];
    const int*   fh   = (const int*)d_in[11];
    float* out = (float*)d_out;

    const size_t w_elems = (size_t)NHEAD * 9 * CC * CC;   // 23,887,872
    const size_t f_elems = (size_t)MM * CC;               //  2,211,840

    ushort_t* ws_whi = (ushort_t*)d_ws;
    ushort_t* ws_wlo = ws_whi + w_elems;
    ushort_t* ws_fhi = ws_wlo + w_elems;
    ushort_t* ws_flo = ws_fhi + f_elems;
    float*    ws_maps = (float*)(ws_flo + f_elems);

    k_single<<<NB, 256, 0, stream>>>(f, linW, linb, out);
    k_prep_w<<<NHEAD * CC, 256, 0, stream>>>(w1, ws_whi, ws_wlo);
    k_prep_f<<<dim3(CC / 32, (PP + 31) / 32, NB), 256, 0, stream>>>(f, ws_fhi, ws_flo);
    k_maps_init<<<(NB * 14 * PP + 255) / 256, 256, 0, stream>>>(ws_maps, b2);
    k_conv_mfma<<<dim3(MM / 256, CC / 64, NHEAD), 256, 0, stream>>>(
        ws_fhi, ws_flo, ws_whi, ws_wlo, w2, bng, bnb, bnm, bnv, ws_maps);
    k_decode<<<NB, 256, 0, stream>>>(ws_maps, fw, fh, out);
}